// Round 1
// baseline (519.906 us; speedup 1.0000x reference)
//
#include <hip/hip_runtime.h>

// Shapes: x1[8,256,128,128] f32, x2[8,128,256,256] f32, w1[1,256], b1[1], wt[2,2], bt[1]
// out[8,128,256,256] f32.
// K1 (unchanged): y[b,h,w] = sum_c x1[b,c,h,w]*w1[c] + b1   (y -> ws, 512 KiB)
// K2a: gate map gmap[b,hu,wu] = 1 + sigmoid(bilateral(y_upsampled))  (2 MiB -> ws)
// K2b: out = x2 * gmap, pure linear float4 grid-stride stream (gmap is L2-hot)

#define B     8
#define CIN   256
#define H     128
#define W     128
#define C2    128
#define HU    256
#define WU    256

__global__ __launch_bounds__(256) void conv1x1_kernel(
    const float* __restrict__ x1, const float* __restrict__ w1,
    const float* __restrict__ b1, float* __restrict__ y)
{
    __shared__ float wsh[CIN];
    __shared__ float4 sred[256];
    int tid = threadIdx.x;
    wsh[tid] = w1[tid];
    __syncthreads();

    // block -> 256 consecutive pixels of batch b
    int b      = blockIdx.x >> 6;              // 64 blocks per batch image
    int hwbase = (blockIdx.x & 63) * 256;      // pixel offset within image

    int q  = tid & 63;                          // float4 pixel-group 0..63
    int cc = tid >> 6;                          // channel chunk 0..3 (64 ch each)

    const float4* p = (const float4*)(x1 + (size_t)b * CIN * H * W + hwbase) + q;
    const int cstride = H * W / 4;              // 4096 float4 per channel

    float4 acc = make_float4(0.f, 0.f, 0.f, 0.f);
    int c0 = cc * 64;
    #pragma unroll 8
    for (int k = 0; k < 64; ++k) {
        int c = c0 + k;
        float4 v = p[(size_t)c * cstride];
        float wv = wsh[c];
        acc.x += v.x * wv; acc.y += v.y * wv;
        acc.z += v.z * wv; acc.w += v.w * wv;
    }
    sred[tid] = acc;
    __syncthreads();

    if (cc == 0) {
        float4 a = sred[q], b2 = sred[q + 64], c2 = sred[q + 128], d2 = sred[q + 192];
        float bias = b1[0];
        float4 r;
        r.x = a.x + b2.x + c2.x + d2.x + bias;
        r.y = a.y + b2.y + c2.y + d2.y + bias;
        r.z = a.z + b2.z + c2.z + d2.z + bias;
        r.w = a.w + b2.w + c2.w + d2.w + bias;
        ((float4*)(y + (size_t)b * H * W + hwbase))[q] = r;
    }
}

__device__ __forceinline__ int refl(int i, int n) {
    // jnp.pad mode='reflect' (no edge repeat): -1 -> 1, n -> n-2
    return i < 0 ? -i : (i >= n ? 2 * n - 2 - i : i);
}

// K2a: one gate per thread. 2048 blocks x 256 threads = 524288 gates.
__global__ __launch_bounds__(256) void gate_map_kernel(
    const float* __restrict__ y, const float* __restrict__ wt,
    const float* __restrict__ bt, float* __restrict__ gmap)
{
    int hu = blockIdx.x & 255;
    int b  = blockIdx.x >> 8;
    int wu = threadIdx.x;

    const float* yb = y + (size_t)b * (H * W);
    float w00 = wt[0], w01 = wt[1], w10 = wt[2], w11 = wt[3];
    float btv = bt[0];

    float u[3][3];
    #pragma unroll
    for (int r = 0; r < 3; ++r) {
        int i  = refl(hu - 1 + r, HU);
        int iy = (i >> 1) * W;
        float wr0 = (i & 1) ? w10 : w00;
        float wr1 = (i & 1) ? w11 : w01;
        #pragma unroll
        for (int c = 0; c < 3; ++c) {
            int j = refl(wu - 1 + c, WU);
            u[r][c] = yb[iy + (j >> 1)] * ((j & 1) ? wr1 : wr0) + btv;
        }
    }

    const float inv2s2 = 0.78125f;          // 1/(2*0.8^2)
    const float e1 = expf(-inv2s2);
    float k1v[3] = { e1, 1.f, e1 };

    float ctr = u[1][1];
    float num = 0.f, den = 0.f;
    #pragma unroll
    for (int r = 0; r < 3; ++r) {
        #pragma unroll
        for (int c = 0; c < 3; ++c) {
            float pv = u[r][c];
            float d  = pv - ctr;
            float w  = expf(-(d * d) * inv2s2) * (k1v[r] * k1v[c]);
            num += w * pv;
            den += w;
        }
    }
    float f = num / den;
    float g = 1.f / (1.f + expf(-f));
    // gmap laid out [b][hu][wu] = [blockIdx.x][wu]
    gmap[(size_t)blockIdx.x * WU + wu] = 1.f + g;   // out = x2 * (1 + gate)
}

// K2b: out = x2 * gmap, linear float4 stream.
// idx (float4 units): b = idx>>21 (C2*HU*WU/4 = 2^21 per batch),
// pixel-group pg = idx & (HU*WU/4 - 1) = idx & 16383; gmap4 index = (b<<14)|pg.
__global__ __launch_bounds__(256) void scale_stream_kernel(
    const float* __restrict__ x2, const float* __restrict__ gmap,
    float* __restrict__ out)
{
    const size_t total  = (size_t)B * C2 * HU * WU / 4;   // 16777216 float4
    const size_t stride = (size_t)gridDim.x * blockDim.x;
    const float4* xp = (const float4*)x2;
    const float4* gp = (const float4*)gmap;
    float4*       op = (float4*)out;

    for (size_t idx = (size_t)blockIdx.x * blockDim.x + threadIdx.x;
         idx < total; idx += stride) {
        size_t gidx = ((idx >> 21) << 14) | (idx & 16383);
        float4 sc = gp[gidx];                 // L2-hot 2 MiB map
        float4 v  = xp[idx];
        v.x *= sc.x; v.y *= sc.y; v.z *= sc.z; v.w *= sc.w;
        op[idx] = v;
    }
}

extern "C" void kernel_launch(void* const* d_in, const int* in_sizes, int n_in,
                              void* d_out, int out_size, void* d_ws, size_t ws_size,
                              hipStream_t stream) {
    const float* x1 = (const float*)d_in[0];
    const float* x2 = (const float*)d_in[1];
    const float* w1 = (const float*)d_in[2];
    const float* b1 = (const float*)d_in[3];
    const float* bt = (const float*)d_in[5];
    const float* wt = (const float*)d_in[4];
    float* out  = (float*)d_out;
    float* y    = (float*)d_ws;                        // 131072 floats = 512 KiB
    float* gmap = (float*)d_ws + (size_t)H * W * B;    // + 2 MiB (8*256*256 floats)

    conv1x1_kernel<<<512, 256, 0, stream>>>(x1, w1, b1, y);
    gate_map_kernel<<<B * HU, 256, 0, stream>>>(y, wt, bt, gmap);
    scale_stream_kernel<<<2048, 256, 0, stream>>>(x2, gmap, out);
}

// Round 3
// 514.391 us; speedup vs baseline: 1.0107x; 1.0107x over previous
//
#include <hip/hip_runtime.h>

// Shapes: x1[8,256,128,128] f32, x2[8,128,256,256] f32, w1[1,256], b1[1], wt[2,2], bt[1]
// out[8,128,256,256] f32.
// K1: y[b,h,w] = sum_c x1[b,c,h,w]*w1[c] + b1   (y -> ws, 512 KiB). NT x1 reads.
// K2a: gate map gmap[b,hu,wu] = 1 + sigmoid(bilateral(y_upsampled))  (2 MiB -> ws)
// K2b: out = x2 * gmap, linear float4 grid-stride stream. NT x2/out, cached gmap.
// NT builtins need native vector types -> use ext_vector_type(4) "f4", not float4.

#define B     8
#define CIN   256
#define H     128
#define W     128
#define C2    128
#define HU    256
#define WU    256

typedef float f4 __attribute__((ext_vector_type(4)));

__global__ __launch_bounds__(256) void conv1x1_kernel(
    const float* __restrict__ x1, const float* __restrict__ w1,
    const float* __restrict__ b1, float* __restrict__ y)
{
    __shared__ float wsh[CIN];
    __shared__ f4 sred[256];
    int tid = threadIdx.x;
    wsh[tid] = w1[tid];
    __syncthreads();

    // block -> 256 consecutive pixels of batch b
    int b      = blockIdx.x >> 6;              // 64 blocks per batch image
    int hwbase = (blockIdx.x & 63) * 256;      // pixel offset within image

    int q  = tid & 63;                          // float4 pixel-group 0..63
    int cc = tid >> 6;                          // channel chunk 0..3 (64 ch each)

    const f4* p = (const f4*)(x1 + (size_t)b * CIN * H * W + hwbase) + q;
    const int cstride = H * W / 4;              // 4096 float4 per channel

    f4 acc = (f4)(0.f);
    int c0 = cc * 64;
    #pragma unroll 16
    for (int k = 0; k < 64; ++k) {
        int c = c0 + k;
        f4 v = __builtin_nontemporal_load(&p[(size_t)c * cstride]);
        float wv = wsh[c];
        acc += v * wv;
    }
    sred[tid] = acc;
    __syncthreads();

    if (cc == 0) {
        f4 r = sred[q] + sred[q + 64] + sred[q + 128] + sred[q + 192] + b1[0];
        ((f4*)(y + (size_t)b * H * W + hwbase))[q] = r;
    }
}

__device__ __forceinline__ int refl(int i, int n) {
    // jnp.pad mode='reflect' (no edge repeat): -1 -> 1, n -> n-2
    return i < 0 ? -i : (i >= n ? 2 * n - 2 - i : i);
}

// K2a: one gate per thread. 2048 blocks x 256 threads = 524288 gates.
__global__ __launch_bounds__(256) void gate_map_kernel(
    const float* __restrict__ y, const float* __restrict__ wt,
    const float* __restrict__ bt, float* __restrict__ gmap)
{
    int hu = blockIdx.x & 255;
    int b  = blockIdx.x >> 8;
    int wu = threadIdx.x;

    const float* yb = y + (size_t)b * (H * W);
    float w00 = wt[0], w01 = wt[1], w10 = wt[2], w11 = wt[3];
    float btv = bt[0];

    float u[3][3];
    #pragma unroll
    for (int r = 0; r < 3; ++r) {
        int i  = refl(hu - 1 + r, HU);
        int iy = (i >> 1) * W;
        float wr0 = (i & 1) ? w10 : w00;
        float wr1 = (i & 1) ? w11 : w01;
        #pragma unroll
        for (int c = 0; c < 3; ++c) {
            int j = refl(wu - 1 + c, WU);
            u[r][c] = yb[iy + (j >> 1)] * ((j & 1) ? wr1 : wr0) + btv;
        }
    }

    const float inv2s2 = 0.78125f;          // 1/(2*0.8^2)
    const float e1 = expf(-inv2s2);
    float k1v[3] = { e1, 1.f, e1 };

    float ctr = u[1][1];
    float num = 0.f, den = 0.f;
    #pragma unroll
    for (int r = 0; r < 3; ++r) {
        #pragma unroll
        for (int c = 0; c < 3; ++c) {
            float pv = u[r][c];
            float d  = pv - ctr;
            float w  = expf(-(d * d) * inv2s2) * (k1v[r] * k1v[c]);
            num += w * pv;
            den += w;
        }
    }
    float f = num / den;
    float g = 1.f / (1.f + expf(-f));
    // gmap laid out [b][hu][wu] = [blockIdx.x][wu]
    gmap[(size_t)blockIdx.x * WU + wu] = 1.f + g;   // out = x2 * (1 + gate)
}

// K2b: out = x2 * gmap, linear float4 stream.
// idx (float4 units): b = idx>>21 (C2*HU*WU/4 = 2^21 per batch),
// pixel-group pg = idx & (HU*WU/4 - 1) = idx & 16383; gmap4 index = (b<<14)|pg.
__global__ __launch_bounds__(256) void scale_stream_kernel(
    const float* __restrict__ x2, const float* __restrict__ gmap,
    float* __restrict__ out)
{
    const size_t total  = (size_t)B * C2 * HU * WU / 4;   // 16777216 float4
    const size_t stride = (size_t)gridDim.x * blockDim.x;
    const f4* xp = (const f4*)x2;
    const f4* gp = (const f4*)gmap;
    f4*       op = (f4*)out;

    for (size_t idx = (size_t)blockIdx.x * blockDim.x + threadIdx.x;
         idx < total; idx += stride) {
        size_t gidx = ((idx >> 21) << 14) | (idx & 16383);
        f4 sc = gp[gidx];                     // L2-hot 2 MiB map (cached read)
        f4 v  = __builtin_nontemporal_load(&xp[idx]);
        v *= sc;
        __builtin_nontemporal_store(v, &op[idx]);
    }
}

extern "C" void kernel_launch(void* const* d_in, const int* in_sizes, int n_in,
                              void* d_out, int out_size, void* d_ws, size_t ws_size,
                              hipStream_t stream) {
    const float* x1 = (const float*)d_in[0];
    const float* x2 = (const float*)d_in[1];
    const float* w1 = (const float*)d_in[2];
    const float* b1 = (const float*)d_in[3];
    const float* wt = (const float*)d_in[4];
    const float* bt = (const float*)d_in[5];
    float* out  = (float*)d_out;
    float* y    = (float*)d_ws;                        // 131072 floats = 512 KiB
    float* gmap = (float*)d_ws + (size_t)H * W * B;    // + 2 MiB (8*256*256 floats)

    conv1x1_kernel<<<512, 256, 0, stream>>>(x1, w1, b1, y);
    gate_map_kernel<<<B * HU, 256, 0, stream>>>(y, wt, bt, gmap);
    scale_stream_kernel<<<2048, 256, 0, stream>>>(x2, gmap, out);
}